// Round 4
// baseline (18376.947 us; speedup 1.0000x reference)
//
#include <hip/hip_runtime.h>

// EA-LSTM fused kernel, v5: full fp32, 2-CU teams, register+LDS-resident weights.
//
// v4 post-mortem: PASSED (absmax 0.5) but 18.3 ms. VGPR_Count=128 proves the
// weight arrays spilled: __launch_bounds__(512,2) means min 2 BLOCKS/CU
// (CUDA semantics) -> 4 waves/SIMD -> 128-VGPR cap < 192-float weight array.
// FETCH_SIZE=19.1 GB @ 1.09 TB/s = the entire runtime was scratch reloads.
//
// v5 fixes residency:
//  - __launch_bounds__(512, 1): 1 block/CU -> 2 waves/SIMD -> 256-VGPR cap.
//  - Per-thread register ask cut 192->160 (wf[64], wo[64], wg[32]; ~205 total
//    VGPR need incl. addressing -> slack under the 256 cap). The other 32
//    g-gate rows live in LDS (64 KB, lane-contiguous float4 -> conflict-free,
//    512 cyc/step on the LDS pipe, hidden under 1728 FMA cyc).
//  - Same-XCD pairing: role=blk>>7, team=blk&127 (partners b, b+128 land on
//    the same XCD under round-robin blk%8) -> h-exchange stays in one L2.
//
// Everything else is v4's verified structure: team of 2 CUs splits the 768
// W_hh columns (role owns units [128r,128r+128), all 256 K-rows), processes
// 2 batch elements (team, team+128) per 365-step pass; per-step cross-CU
// h-exchange through hn_out (written anyway) with agent-scope release/acquire
// on a monotone step-flag in d_ws; startup rendezvous through cn_out row 364
// (harness memsets d_out pre-launch -> stale-ws/replay safe).

#define BB 256
#define SS 365
#define FD 32
#define FS 27
#define HH 256
#define NT 512
typedef unsigned int u32;

struct Smem {
    float wih[FD][3][128];                  // 48 KB  W_ih half (this role's cols)
    __align__(16) float4 wgl[4][8][128];    // 64 KB  g-gate rows 32..63 of each kq-chunk
    float part[2][3][4][128];               // 12 KB  partials [elem][gate][kq][a]
    float hbuf[2][128];                     // own-half h per elem
    float xbuf[2][2][FD];                   // x rows, double-buffered
    float outp[2][2];                       // fc wave partials
};

#define MAC4(HA, HB, WF, WO, WG) \
    acc00 = fmaf(HA, WF, acc00); acc01 = fmaf(HA, WO, acc01); acc02 = fmaf(HA, WG, acc02); \
    acc10 = fmaf(HB, WF, acc10); acc11 = fmaf(HB, WO, acc11); acc12 = fmaf(HB, WG, acc12);

// rows 4J..4J+3 with all-register weights (J = 0..7)
#define MAC16R(A, B, J) \
    MAC4(A.x, B.x, wf[4*(J)+0], wo[4*(J)+0], wg[4*(J)+0]) \
    MAC4(A.y, B.y, wf[4*(J)+1], wo[4*(J)+1], wg[4*(J)+1]) \
    MAC4(A.z, B.z, wf[4*(J)+2], wo[4*(J)+2], wg[4*(J)+2]) \
    MAC4(A.w, B.w, wf[4*(J)+3], wo[4*(J)+3], wg[4*(J)+3])

// rows 4J..4J+3, g-gate weights from LDS float4 (J = 8..15)
#define MAC16L(A, B, J, W) \
    MAC4(A.x, B.x, wf[4*(J)+0], wo[4*(J)+0], (W).x) \
    MAC4(A.y, B.y, wf[4*(J)+1], wo[4*(J)+1], (W).y) \
    MAC4(A.z, B.z, wf[4*(J)+2], wo[4*(J)+2], (W).z) \
    MAC4(A.w, B.w, wf[4*(J)+3], wo[4*(J)+3], (W).w)

__global__ __launch_bounds__(NT, 1) void ealstm_kernel(
    const float* __restrict__ x_d, const float* __restrict__ x_s,
    const float* __restrict__ W_ih, const float* __restrict__ W_hh,
    const float* __restrict__ W_sh, const float* __restrict__ bias,
    const float* __restrict__ bias_s, const float* __restrict__ W_fc,
    const float* __restrict__ b_fc, float* __restrict__ d_out,
    u32* __restrict__ ws)
{
    extern __shared__ __align__(16) unsigned char smem_raw[];
    Smem& sm = *reinterpret_cast<Smem*>(smem_raw);

    const int t = threadIdx.x;
    const int blk = blockIdx.x;
    const int role = blk >> 7, team = blk & 127;   // partners: blk, blk+128 (same XCD)
    const int e0 = team, e1 = team + 128;
    const int kq = t >> 7, a = t & 127;
    const bool own_half = ((kq >> 1) == role);     // wave-uniform

    float* __restrict__ out_fc = d_out;                      // [B,S,1]
    float* __restrict__ hn_out = d_out + (size_t)BB * SS;    // [B,S,H]
    float* __restrict__ cn_out = hn_out + (size_t)BB * SS * HH;

    u32* flag_my = ws + (size_t)(team * 2 + role) * 16;
    u32* flag_pt = ws + (size_t)(team * 2 + (1 ^ role)) * 16;
    float* fcp_my = (float*)(ws + 4096) + (team * 2 + role) * 4;
    float* fcp_pt = (float*)(ws + 4096) + (team * 2 + (1 ^ role)) * 4;

    // ---- resident weights: rows [64kq,64kq+64) x cols {128r+a, +256, +512}
    // wf/wo: all 64 rows in regs. wg: rows 0..31 in regs, rows 32..63 in LDS.
    float wf[64], wo[64], wg[32];
    {
        const float* base = W_hh + (size_t)(64 * kq) * 768 + 128 * role + a;
#pragma unroll
        for (int j = 0; j < 64; ++j) {
            wf[j] = base[(size_t)j * 768];
            wo[j] = base[(size_t)j * 768 + 256];
        }
#pragma unroll
        for (int j = 0; j < 32; ++j)
            wg[j] = base[(size_t)j * 768 + 512];
#pragma unroll
        for (int jj = 0; jj < 8; ++jj) {
            const float* p = base + (size_t)(32 + 4 * jj) * 768 + 512;
            sm.wgl[kq][jj][a] = make_float4(p[0], p[768], p[2 * 768], p[3 * 768]);
        }
    }
    // ---- W_ih half -> LDS
    for (int idx = t; idx < FD * 384; idx += NT) {
        const int k = idx / 384, rem = idx - k * 384;
        const int g = rem >> 7, cc = rem & 127;
        sm.wih[k][g][cc] = W_ih[(size_t)k * 768 + g * 256 + 128 * role + cc];
    }
    // ---- x row 0 for both elements
    if (t < 64) {
        const int e = t >> 5, lane = t & 31;
        sm.xbuf[0][e][lane] = x_d[(size_t)(e ? e1 : e0) * SS * FD + lane];
    }
    // ---- gate-lane constants/state (threads 0..255: elem t>>7, unit 128r+(t&127))
    float c_state = 0.f, igv = 0.f, bfv = 0.f, bov = 0.f, bgv = 0.f, wfcv = 0.f;
    if (t < 256) {
        const int e = t >> 7, i = t & 127, u = 128 * role + i;
        const int eb = e ? e1 : e0;
        float accs = bias_s[u];
        for (int k = 0; k < FS; ++k)
            accs = fmaf(x_s[(size_t)eb * FS + k], W_sh[(size_t)k * HH + u], accs);
        igv = 1.f / (1.f + __expf(-accs));
        bfv = bias[u]; bov = bias[HH + u]; bgv = bias[2 * HH + u];
        wfcv = W_fc[u];
        sm.hbuf[e][i] = 0.f;                      // h0 = 0
    }
    const float bfc = b_fc[0];

    // ---- startup rendezvous (stale-ws safe: zero own flag BEFORE ready magic)
    u32* rdy_my = (u32*)(cn_out + ((size_t)e0 * SS + (SS - 1)) * HH + 128 * role);
    u32* rdy_pt = (u32*)(cn_out + ((size_t)e0 * SS + (SS - 1)) * HH + 128 * (1 ^ role));
    if (t == 0) {
        __hip_atomic_store(flag_my, 0u, __ATOMIC_RELAXED, __HIP_MEMORY_SCOPE_AGENT);
        __threadfence();
        __hip_atomic_store(rdy_my, 0x3F800000u, __ATOMIC_RELEASE, __HIP_MEMORY_SCOPE_AGENT);
        while (__hip_atomic_load(rdy_pt, __ATOMIC_ACQUIRE, __HIP_MEMORY_SCOPE_AGENT)
               != 0x3F800000u) {}
    }
    __syncthreads();

    for (int s = 0; s < SS; ++s) {
        const int par = s & 1;
        // ---- publish step s: h row s-1 (drained by barrier) + fc partials
        if (t == 0 && s > 0) {
            fcp_my[((s - 1) & 1) * 2 + 0] = sm.outp[0][0] + sm.outp[0][1];
            fcp_my[((s - 1) & 1) * 2 + 1] = sm.outp[1][0] + sm.outp[1][1];
            __threadfence();
            __hip_atomic_store(flag_my, (u32)s, __ATOMIC_RELEASE, __HIP_MEMORY_SCOPE_AGENT);
        }
        // ---- x prefetch for s+1 (wave-4 lanes; lands after the mid barrier)
        float xpre = 0.f; const int xi = t - 256;
        if (xi >= 0 && xi < 64) {
            const int xe = xi >> 5, xl = xi & 31;
            const int sn = (s + 1 < SS) ? s + 1 : SS - 1;
            xpre = x_d[(size_t)(xe ? e1 : e0) * SS * FD + (size_t)sn * FD + xl];
        }
        // ---- x-projection share (rows 8kq..8kq+7)
        float acc00 = 0, acc01 = 0, acc02 = 0, acc10 = 0, acc11 = 0, acc12 = 0;
        {
            const int x0 = 8 * kq;
#pragma unroll
            for (int jj = 0; jj < 8; ++jj) {
                const float xv0 = sm.xbuf[par][0][x0 + jj], xv1 = sm.xbuf[par][1][x0 + jj];
                const float w0 = sm.wih[x0 + jj][0][a];
                const float w1 = sm.wih[x0 + jj][1][a];
                const float w2 = sm.wih[x0 + jj][2][a];
                acc00 = fmaf(xv0, w0, acc00); acc01 = fmaf(xv0, w1, acc01); acc02 = fmaf(xv0, w2, acc02);
                acc10 = fmaf(xv1, w0, acc10); acc11 = fmaf(xv1, w1, acc11); acc12 = fmaf(xv1, w2, acc12);
            }
        }
        // ---- h @ W_hh quarter (skip at s=0: h=0)
        if (s > 0) {
            if (own_half) {
                const float4* h0 = reinterpret_cast<const float4*>(&sm.hbuf[0][64 * (kq & 1)]);
                const float4* h1 = reinterpret_cast<const float4*>(&sm.hbuf[1][64 * (kq & 1)]);
#pragma unroll
                for (int j4 = 0; j4 < 8; ++j4) {
                    const float4 A = h0[j4], B = h1[j4];
                    MAC16R(A, B, j4)
                }
#pragma unroll
                for (int j4 = 8; j4 < 16; ++j4) {
                    const float4 A = h0[j4], B = h1[j4];
                    const float4 W = sm.wgl[kq][j4 - 8][a];
                    MAC16L(A, B, j4, W)
                }
            } else {
                while ((int)__hip_atomic_load(flag_pt, __ATOMIC_ACQUIRE,
                                              __HIP_MEMORY_SCOPE_AGENT) < s) {}
                const float4* h0 = reinterpret_cast<const float4*>(
                    hn_out + ((size_t)e0 * SS + (s - 1)) * HH + 128 * (1 ^ role) + 64 * (kq & 1));
                const float4* h1 = reinterpret_cast<const float4*>(
                    hn_out + ((size_t)e1 * SS + (s - 1)) * HH + 128 * (1 ^ role) + 64 * (kq & 1));
#pragma unroll
                for (int j4 = 0; j4 < 8; ++j4) {
                    const float4 A = h0[j4], B = h1[j4];
                    MAC16R(A, B, j4)
                }
#pragma unroll
                for (int j4 = 8; j4 < 16; ++j4) {
                    const float4 A = h0[j4], B = h1[j4];
                    const float4 W = sm.wgl[kq][j4 - 8][a];
                    MAC16L(A, B, j4, W)
                }
            }
        }
        // ---- deferred fc head write for s-1 (role 0; this wave already acquired flag>=s)
        if (role == 0 && t == 256 && s > 0) {
            const int pp = (s - 1) & 1;
            out_fc[(size_t)e0 * SS + (s - 1)] = sm.outp[0][0] + sm.outp[0][1] + fcp_pt[pp * 2 + 0] + bfc;
            out_fc[(size_t)e1 * SS + (s - 1)] = sm.outp[1][0] + sm.outp[1][1] + fcp_pt[pp * 2 + 1] + bfc;
        }
        // ---- partials + land prefetched x
        sm.part[0][0][kq][a] = acc00; sm.part[0][1][kq][a] = acc01; sm.part[0][2][kq][a] = acc02;
        sm.part[1][0][kq][a] = acc10; sm.part[1][1][kq][a] = acc11; sm.part[1][2][kq][a] = acc12;
        if (xi >= 0 && xi < 64) sm.xbuf[par ^ 1][xi >> 5][xi & 31] = xpre;
        __syncthreads();

        // ---- gate phase (threads 0..255)
        if (t < 256) {
            const int e = t >> 7, i = t & 127;
            float f = sm.part[e][0][0][i] + sm.part[e][0][1][i] + sm.part[e][0][2][i] + sm.part[e][0][3][i] + bfv;
            float o = sm.part[e][1][0][i] + sm.part[e][1][1][i] + sm.part[e][1][2][i] + sm.part[e][1][3][i] + bov;
            float g = sm.part[e][2][0][i] + sm.part[e][2][1][i] + sm.part[e][2][2][i] + sm.part[e][2][3][i] + bgv;
            const float sf = 1.f / (1.f + __expf(-f));
            const float so = 1.f / (1.f + __expf(-o));
            const float tg = 1.f - 2.f / (1.f + __expf(2.f * g));   // safe tanh
            c_state = sf * c_state + igv * tg;
            const float tc = 1.f - 2.f / (1.f + __expf(2.f * c_state));
            const float h1 = so * tc;
            sm.hbuf[e][i] = h1;
            const size_t oidx = ((size_t)(e ? e1 : e0) * SS + s) * HH + 128 * role + i;
            hn_out[oidx] = h1;
            cn_out[oidx] = c_state;
            float psum = h1 * wfcv;
#pragma unroll
            for (int d = 32; d > 0; d >>= 1) psum += __shfl_down(psum, d);
            if ((t & 63) == 0) sm.outp[t >> 7][(t >> 6) & 1] = psum;
        }
        __syncthreads();   // drains hn/cn stores (vmcnt 0) before next publish
    }

    // ---- epilogue: final publish + fc row 364
    if (t == 0) {
        fcp_my[0] = sm.outp[0][0] + sm.outp[0][1];
        fcp_my[1] = sm.outp[1][0] + sm.outp[1][1];
        __threadfence();
        __hip_atomic_store(flag_my, (u32)SS, __ATOMIC_RELEASE, __HIP_MEMORY_SCOPE_AGENT);
        if (role == 0) {
            while ((int)__hip_atomic_load(flag_pt, __ATOMIC_ACQUIRE,
                                          __HIP_MEMORY_SCOPE_AGENT) < SS) {}
            out_fc[(size_t)e0 * SS + (SS - 1)] = sm.outp[0][0] + sm.outp[0][1] + fcp_pt[0] + bfc;
            out_fc[(size_t)e1 * SS + (SS - 1)] = sm.outp[1][0] + sm.outp[1][1] + fcp_pt[1] + bfc;
        }
    }
}

extern "C" void kernel_launch(void* const* d_in, const int* in_sizes, int n_in,
                              void* d_out, int out_size, void* d_ws, size_t ws_size,
                              hipStream_t stream) {
    const float* x_d    = (const float*)d_in[0];
    const float* x_s    = (const float*)d_in[1];
    const float* W_ih   = (const float*)d_in[2];
    const float* W_hh   = (const float*)d_in[3];
    const float* W_sh   = (const float*)d_in[4];
    const float* bias   = (const float*)d_in[5];
    const float* bias_s = (const float*)d_in[6];
    const float* W_fc   = (const float*)d_in[7];
    const float* b_fc   = (const float*)d_in[8];

    static bool smem_set = false;
    if (!smem_set) {
        hipFuncSetAttribute((const void*)ealstm_kernel,
                            hipFuncAttributeMaxDynamicSharedMemorySize,
                            (int)sizeof(Smem));
        smem_set = true;
    }

    ealstm_kernel<<<dim3(BB), dim3(NT), sizeof(Smem), stream>>>(
        x_d, x_s, W_ih, W_hh, W_sh, bias, bias_s, W_fc, b_fc,
        (float*)d_out, (u32*)d_ws);
}